// Round 1
// baseline (263.063 us; speedup 1.0000x reference)
//
#include <hip/hip_runtime.h>
#include <stdint.h>

#define HIDDEN 1024
#define MROWS  32768
#define NPROTO 9
#define ZOFF   (MROWS * NPROTO)   // 294912 floats of logits, then z

typedef __bf16 bf16x8 __attribute__((ext_vector_type(8)));
typedef float  f32x4  __attribute__((ext_vector_type(4)));

__device__ __forceinline__ unsigned short f2bf(float f) {
    unsigned u = __float_as_uint(f);
    u += 0x7fffu + ((u >> 16) & 1u);   // round-to-nearest-even
    return (unsigned short)(u >> 16);
}

// ---------------- prep: h (f32) -> bf16 ----------------
__global__ void k_conv_h(const float* __restrict__ src, unsigned short* __restrict__ dst, int n8) {
    int i0 = blockIdx.x * blockDim.x + threadIdx.x;
    int stride = gridDim.x * blockDim.x;
    for (int i = i0; i < n8; i += stride) {
        const float4* p = (const float4*)(src + (size_t)i * 8);
        float4 a = p[0], b = p[1];
        union { unsigned short us[8]; uint4 v; } o;
        o.us[0] = f2bf(a.x); o.us[1] = f2bf(a.y); o.us[2] = f2bf(a.z); o.us[3] = f2bf(a.w);
        o.us[4] = f2bf(b.x); o.us[5] = f2bf(b.y); o.us[6] = f2bf(b.z); o.us[7] = f2bf(b.w);
        *(uint4*)(dst + (size_t)i * 8) = o.v;
    }
}

// ---------------- prep: W*mask -> bf16 ----------------
__global__ void k_conv_w(const float* __restrict__ w, const float* __restrict__ m,
                         unsigned short* __restrict__ dst, int n8) {
    int i0 = blockIdx.x * blockDim.x + threadIdx.x;
    int stride = gridDim.x * blockDim.x;
    for (int i = i0; i < n8; i += stride) {
        const float4* pw = (const float4*)(w + (size_t)i * 8);
        const float4* pm = (const float4*)(m + (size_t)i * 8);
        float4 a = pw[0], b = pw[1], c = pm[0], d = pm[1];
        union { unsigned short us[8]; uint4 v; } o;
        o.us[0] = f2bf(a.x * c.x); o.us[1] = f2bf(a.y * c.y);
        o.us[2] = f2bf(a.z * c.z); o.us[3] = f2bf(a.w * c.w);
        o.us[4] = f2bf(b.x * d.x); o.us[5] = f2bf(b.y * d.y);
        o.us[6] = f2bf(b.z * d.z); o.us[7] = f2bf(b.w * d.w);
        *(uint4*)(dst + (size_t)i * 8) = o.v;
    }
}

// ---------------- prep: l2-normalized prototypes (first 9 rows) ----------------
__global__ void k_proto(const float* __restrict__ proto, float* __restrict__ pn) {
    __shared__ float red[4];
    int t = threadIdx.x, k = blockIdx.x;
    float4 v = *(const float4*)(proto + (size_t)k * HIDDEN + t * 4);
    float ss = v.x * v.x + v.y * v.y + v.z * v.z + v.w * v.w;
    #pragma unroll
    for (int m = 1; m < 64; m <<= 1) ss += __shfl_xor(ss, m);
    if ((t & 63) == 0) red[t >> 6] = ss;
    __syncthreads();
    ss = red[0] + red[1] + red[2] + red[3];
    float inv = 1.0f / fmaxf(sqrtf(ss), 1e-12f);
    float4 o; o.x = v.x * inv; o.y = v.y * inv; o.z = v.z * inv; o.w = v.w * inv;
    *(float4*)(pn + (size_t)k * HIDDEN + t * 4) = o;
}

// ---------------- main GEMM: z_pre[m][o] = sum_d hb[m][d] * wm[o][d] ----------------
// 128x128 tile, BK=32, 4 waves (2x2), 16x16x32 bf16 MFMA, global_load_lds staging.
__global__ __launch_bounds__(256, 2) void k_gemm(const unsigned short* __restrict__ A,
                                                 const unsigned short* __restrict__ B,
                                                 float* __restrict__ C) {
    __shared__ unsigned short As[2][128 * 32];
    __shared__ unsigned short Bs[2][128 * 32];
    const int tid = threadIdx.x;
    const int wid = tid >> 6, lane = tid & 63;
    const int bm0 = (int)(blockIdx.x >> 3) * 128;
    const int bn0 = (int)(blockIdx.x & 7) * 128;
    const int wr = wid >> 1, wc = wid & 1;
    const int fr = lane & 15, kq = lane >> 4;

    f32x4 acc[4][4] = {};

    auto stage = [&](int buf, int k0) {
        #pragma unroll
        for (int is = 0; is < 2; ++is) {
            int c = is * 256 + tid;
            int row = c >> 2, seg = c & 3;
            const unsigned short* ga = A + (size_t)(bm0 + row) * HIDDEN + k0 + seg * 8;
            void* la = (void*)((char*)&As[buf][0] + (size_t)(is * 256 + wid * 64) * 16);
            __builtin_amdgcn_global_load_lds((const __attribute__((address_space(1))) void*)ga,
                                             (__attribute__((address_space(3))) void*)la, 16, 0, 0);
            const unsigned short* gb = B + (size_t)(bn0 + row) * HIDDEN + k0 + seg * 8;
            void* lb = (void*)((char*)&Bs[buf][0] + (size_t)(is * 256 + wid * 64) * 16);
            __builtin_amdgcn_global_load_lds((const __attribute__((address_space(1))) void*)gb,
                                             (__attribute__((address_space(3))) void*)lb, 16, 0, 0);
        }
    };

    auto compute = [&](int buf) {
        bf16x8 av[4], bv[4];
        #pragma unroll
        for (int i = 0; i < 4; i++)
            av[i] = *(const bf16x8*)&As[buf][(wr * 64 + i * 16 + fr) * 32 + kq * 8];
        #pragma unroll
        for (int j = 0; j < 4; j++)
            bv[j] = *(const bf16x8*)&Bs[buf][(wc * 64 + j * 16 + fr) * 32 + kq * 8];
        #pragma unroll
        for (int i = 0; i < 4; i++)
            #pragma unroll
            for (int j = 0; j < 4; j++)
                acc[i][j] = __builtin_amdgcn_mfma_f32_16x16x32_bf16(av[i], bv[j], acc[i][j], 0, 0, 0);
    };

    stage(0, 0);
    __syncthreads();
    int cur = 0;
    for (int t = 1; t < 32; t++) {
        stage(cur ^ 1, t * 32);
        compute(cur);
        __syncthreads();
        cur ^= 1;
    }
    compute(cur);

    #pragma unroll
    for (int i = 0; i < 4; i++) {
        #pragma unroll
        for (int j = 0; j < 4; j++) {
            int col = bn0 + wc * 64 + j * 16 + fr;
            int rowb = bm0 + wr * 64 + i * 16 + kq * 4;
            #pragma unroll
            for (int r = 0; r < 4; r++)
                C[(size_t)(rowb + r) * HIDDEN + col] = acc[i][j][r];
        }
    }
}

// ---------------- LN + l2norm + prototype logits (in-place on z) ----------------
__global__ __launch_bounds__(256) void k_ln(float* __restrict__ z, float* __restrict__ logits,
                                            const float* __restrict__ gamma, const float* __restrict__ beta,
                                            const float* __restrict__ pn) {
    __shared__ float red[4][12];
    const int tid = threadIdx.x, wid = tid >> 6, lane = tid & 63;
    const int col = tid * 4;
    float4 g4 = *(const float4*)(gamma + col);
    float4 b4 = *(const float4*)(beta + col);
    float pr[9][4];
    #pragma unroll
    for (int k = 0; k < 9; k++) {
        float4 p = *(const float4*)(pn + k * HIDDEN + col);
        pr[k][0] = p.x; pr[k][1] = p.y; pr[k][2] = p.z; pr[k][3] = p.w;
    }
    for (int r = 0; r < 8; r++) {
        size_t row = (size_t)blockIdx.x * 8 + r;
        float* zr = z + row * HIDDEN;
        float4 v = *(const float4*)(zr + col);
        float s  = v.x + v.y + v.z + v.w;
        float sq = v.x * v.x + v.y * v.y + v.z * v.z + v.w * v.w;
        #pragma unroll
        for (int m = 1; m < 64; m <<= 1) { s += __shfl_xor(s, m); sq += __shfl_xor(sq, m); }
        if (lane == 0) { red[wid][10] = s; red[wid][11] = sq; }
        __syncthreads();
        s  = red[0][10] + red[1][10] + red[2][10] + red[3][10];
        sq = red[0][11] + red[1][11] + red[2][11] + red[3][11];
        const float inv_n = 1.0f / 1024.0f;
        float mu  = s * inv_n;
        float var = sq * inv_n - mu * mu;
        float rs  = rsqrtf(var + 1e-5f);
        float4 zz;
        zz.x = (v.x - mu) * rs * g4.x + b4.x;
        zz.y = (v.y - mu) * rs * g4.y + b4.y;
        zz.z = (v.z - mu) * rs * g4.z + b4.z;
        zz.w = (v.w - mu) * rs * g4.w + b4.w;
        *(float4*)(zr + col) = zz;
        float part[10];
        part[9] = zz.x * zz.x + zz.y * zz.y + zz.z * zz.z + zz.w * zz.w;
        #pragma unroll
        for (int k = 0; k < 9; k++)
            part[k] = zz.x * pr[k][0] + zz.y * pr[k][1] + zz.z * pr[k][2] + zz.w * pr[k][3];
        #pragma unroll
        for (int m = 1; m < 64; m <<= 1) {
            #pragma unroll
            for (int k = 0; k < 10; k++) part[k] += __shfl_xor(part[k], m);
        }
        if (lane == 0) {
            #pragma unroll
            for (int k = 0; k < 10; k++) red[wid][k] = part[k];
        }
        __syncthreads();
        if (wid == 0) {
            float val = 0.0f;
            if (lane < 10) val = red[0][lane] + red[1][lane] + red[2][lane] + red[3][lane];
            float nrm2 = __shfl(val, 9);
            if (lane < 9) {
                float nrm = fmaxf(sqrtf(nrm2), 1e-12f);
                logits[row * NPROTO + lane] = val / (nrm * 0.07f);
            }
        }
        __syncthreads();
    }
}

extern "C" void kernel_launch(void* const* d_in, const int* in_sizes, int n_in,
                              void* d_out, int out_size, void* d_ws, size_t ws_size,
                              hipStream_t stream) {
    const float* h     = (const float*)d_in[0];
    const float* w     = (const float*)d_in[1];
    const float* mask  = (const float*)d_in[2];
    const float* gamma = (const float*)d_in[3];
    const float* beta  = (const float*)d_in[4];
    const float* proto = (const float*)d_in[5];
    float* out    = (float*)d_out;
    float* logits = out;                       // 32768*9 floats
    float* z      = out + (size_t)ZOFF;        // 32768*1024 floats

    char* ws = (char*)d_ws;
    unsigned short* hb = (unsigned short*)ws;                        // 64 MB bf16 h
    unsigned short* wm = (unsigned short*)(ws + 67108864);           // 2 MB bf16 W*mask
    float*          pn = (float*)(ws + 67108864 + 2097152);          // 36 KB normalized protos

    k_conv_h<<<4096, 256, 0, stream>>>(h, hb, MROWS * HIDDEN / 8);
    k_conv_w<<<512, 256, 0, stream>>>(w, mask, wm, HIDDEN * HIDDEN / 8);
    k_proto<<<NPROTO, 256, 0, stream>>>(proto, pn);
    k_gemm<<<2048, 256, 0, stream>>>(hb, wm, z);
    k_ln<<<4096, 256, 0, stream>>>(z, logits, gamma, beta, pn);
}

// Round 2
// 201.468 us; speedup vs baseline: 1.3057x; 1.3057x over previous
//
#include <hip/hip_runtime.h>
#include <stdint.h>

#define HIDDEN 1024
#define MROWS  32768
#define NPROTO 9
#define ZOFF   (MROWS * NPROTO)   // 294912 floats of logits, then z

typedef __bf16 bf16x8 __attribute__((ext_vector_type(8)));
typedef float  f32x4  __attribute__((ext_vector_type(4)));

__device__ __forceinline__ unsigned short f2bf(float f) {
    unsigned u = __float_as_uint(f);
    u += 0x7fffu + ((u >> 16) & 1u);   // round-to-nearest-even
    return (unsigned short)(u >> 16);
}

// ---------------- prep: h (f32) -> bf16 ----------------
__global__ void k_conv_h(const float* __restrict__ src, unsigned short* __restrict__ dst, int n8) {
    int i0 = blockIdx.x * blockDim.x + threadIdx.x;
    int stride = gridDim.x * blockDim.x;
    for (int i = i0; i < n8; i += stride) {
        const float4* p = (const float4*)(src + (size_t)i * 8);
        float4 a = p[0], b = p[1];
        union { unsigned short us[8]; uint4 v; } o;
        o.us[0] = f2bf(a.x); o.us[1] = f2bf(a.y); o.us[2] = f2bf(a.z); o.us[3] = f2bf(a.w);
        o.us[4] = f2bf(b.x); o.us[5] = f2bf(b.y); o.us[6] = f2bf(b.z); o.us[7] = f2bf(b.w);
        *(uint4*)(dst + (size_t)i * 8) = o.v;
    }
}

// ---------------- prep: W*mask -> bf16 ----------------
__global__ void k_conv_w(const float* __restrict__ w, const float* __restrict__ m,
                         unsigned short* __restrict__ dst, int n8) {
    int i0 = blockIdx.x * blockDim.x + threadIdx.x;
    int stride = gridDim.x * blockDim.x;
    for (int i = i0; i < n8; i += stride) {
        const float4* pw = (const float4*)(w + (size_t)i * 8);
        const float4* pm = (const float4*)(m + (size_t)i * 8);
        float4 a = pw[0], b = pw[1], c = pm[0], d = pm[1];
        union { unsigned short us[8]; uint4 v; } o;
        o.us[0] = f2bf(a.x * c.x); o.us[1] = f2bf(a.y * c.y);
        o.us[2] = f2bf(a.z * c.z); o.us[3] = f2bf(a.w * c.w);
        o.us[4] = f2bf(b.x * d.x); o.us[5] = f2bf(b.y * d.y);
        o.us[6] = f2bf(b.z * d.z); o.us[7] = f2bf(b.w * d.w);
        *(uint4*)(dst + (size_t)i * 8) = o.v;
    }
}

// ---------------- prep: l2-normalized prototypes (first 9 rows) ----------------
__global__ void k_proto(const float* __restrict__ proto, float* __restrict__ pn) {
    __shared__ float red[4];
    int t = threadIdx.x, k = blockIdx.x;
    float4 v = *(const float4*)(proto + (size_t)k * HIDDEN + t * 4);
    float ss = v.x * v.x + v.y * v.y + v.z * v.z + v.w * v.w;
    #pragma unroll
    for (int m = 1; m < 64; m <<= 1) ss += __shfl_xor(ss, m);
    if ((t & 63) == 0) red[t >> 6] = ss;
    __syncthreads();
    ss = red[0] + red[1] + red[2] + red[3];
    float inv = 1.0f / fmaxf(sqrtf(ss), 1e-12f);
    float4 o; o.x = v.x * inv; o.y = v.y * inv; o.z = v.z * inv; o.w = v.w * inv;
    *(float4*)(pn + (size_t)k * HIDDEN + t * 4) = o;
}

// ---------------- main GEMM: z_pre[m][o] = sum_d hb[m][d] * wm[o][d] ----------------
// 128x128 tile, BK=32, 4 waves (2x2), 16x16x32 bf16 MFMA, global_load_lds staging.
__global__ __launch_bounds__(256, 2) void k_gemm(const unsigned short* __restrict__ A,
                                                 const unsigned short* __restrict__ B,
                                                 float* __restrict__ C) {
    __shared__ unsigned short As[2][128 * 32];
    __shared__ unsigned short Bs[2][128 * 32];
    const int tid = threadIdx.x;
    const int wid = tid >> 6, lane = tid & 63;
    const int bm0 = (int)(blockIdx.x >> 3) * 128;
    const int bn0 = (int)(blockIdx.x & 7) * 128;
    const int wr = wid >> 1, wc = wid & 1;
    const int fr = lane & 15, kq = lane >> 4;

    f32x4 acc[4][4] = {};

    auto stage = [&](int buf, int k0) {
        #pragma unroll
        for (int is = 0; is < 2; ++is) {
            int c = is * 256 + tid;
            int row = c >> 2, seg = c & 3;
            const unsigned short* ga = A + (size_t)(bm0 + row) * HIDDEN + k0 + seg * 8;
            void* la = (void*)((char*)&As[buf][0] + (size_t)(is * 256 + wid * 64) * 16);
            __builtin_amdgcn_global_load_lds((const __attribute__((address_space(1))) void*)ga,
                                             (__attribute__((address_space(3))) void*)la, 16, 0, 0);
            const unsigned short* gb = B + (size_t)(bn0 + row) * HIDDEN + k0 + seg * 8;
            void* lb = (void*)((char*)&Bs[buf][0] + (size_t)(is * 256 + wid * 64) * 16);
            __builtin_amdgcn_global_load_lds((const __attribute__((address_space(1))) void*)gb,
                                             (__attribute__((address_space(3))) void*)lb, 16, 0, 0);
        }
    };

    auto compute = [&](int buf) {
        bf16x8 av[4], bv[4];
        #pragma unroll
        for (int i = 0; i < 4; i++)
            av[i] = *(const bf16x8*)&As[buf][(wr * 64 + i * 16 + fr) * 32 + kq * 8];
        #pragma unroll
        for (int j = 0; j < 4; j++)
            bv[j] = *(const bf16x8*)&Bs[buf][(wc * 64 + j * 16 + fr) * 32 + kq * 8];
        #pragma unroll
        for (int i = 0; i < 4; i++)
            #pragma unroll
            for (int j = 0; j < 4; j++)
                acc[i][j] = __builtin_amdgcn_mfma_f32_16x16x32_bf16(av[i], bv[j], acc[i][j], 0, 0, 0);
    };

    stage(0, 0);
    __syncthreads();
    int cur = 0;
    for (int t = 1; t < 32; t++) {
        stage(cur ^ 1, t * 32);
        compute(cur);
        __syncthreads();
        cur ^= 1;
    }
    compute(cur);

    #pragma unroll
    for (int i = 0; i < 4; i++) {
        #pragma unroll
        for (int j = 0; j < 4; j++) {
            int col = bn0 + wc * 64 + j * 16 + fr;
            int rowb = bm0 + wr * 64 + i * 16 + kq * 4;
            #pragma unroll
            for (int r = 0; r < 4; r++)
                C[(size_t)(rowb + r) * HIDDEN + col] = acc[i][j][r];
        }
    }
}

// ---------------- LN + l2norm + prototype logits (in-place on z) ----------------
// One WAVE per row, no barriers in the row loop. 64 lanes x 16 cols (4x float4).
// Protos staged in LDS once per block (36 KB -> 4 blocks/CU).
__global__ __launch_bounds__(256) void k_ln(float* __restrict__ z, float* __restrict__ logits,
                                            const float* __restrict__ gamma, const float* __restrict__ beta,
                                            const float* __restrict__ pn, int waves_total) {
    __shared__ float sp[NPROTO * HIDDEN];
    const int tid = threadIdx.x, wid = tid >> 6, lane = tid & 63;
    // stage normalized protos to LDS (once per block)
    #pragma unroll
    for (int i = 0; i < NPROTO * HIDDEN / 4 / 256; i++) {
        int idx = (i * 256 + tid) * 4;
        *(float4*)&sp[idx] = *(const float4*)&pn[idx];
    }
    __syncthreads();

    // hoisted per-lane gamma/beta (cols: lane*4 + 256*c)
    float4 g4[4], b4[4];
    #pragma unroll
    for (int c = 0; c < 4; c++) {
        g4[c] = *(const float4*)(gamma + lane * 4 + 256 * c);
        b4[c] = *(const float4*)(beta  + lane * 4 + 256 * c);
    }

    const float inv_n = 1.0f / 1024.0f;
    int gw = blockIdx.x * 4 + wid;
    for (int row = gw; row < MROWS; row += waves_total) {
        float* zr = z + (size_t)row * HIDDEN;
        float4 v[4];
        #pragma unroll
        for (int c = 0; c < 4; c++) v[c] = *(const float4*)(zr + lane * 4 + 256 * c);

        float s = 0.f, sq = 0.f;
        #pragma unroll
        for (int c = 0; c < 4; c++) {
            s  += v[c].x + v[c].y + v[c].z + v[c].w;
            sq += v[c].x * v[c].x + v[c].y * v[c].y + v[c].z * v[c].z + v[c].w * v[c].w;
        }
        #pragma unroll
        for (int m = 1; m < 64; m <<= 1) { s += __shfl_xor(s, m); sq += __shfl_xor(sq, m); }

        float mu  = s * inv_n;
        float var = sq * inv_n - mu * mu;
        float rs  = rsqrtf(var + 1e-5f);

        #pragma unroll
        for (int c = 0; c < 4; c++) {
            v[c].x = (v[c].x - mu) * rs * g4[c].x + b4[c].x;
            v[c].y = (v[c].y - mu) * rs * g4[c].y + b4[c].y;
            v[c].z = (v[c].z - mu) * rs * g4[c].z + b4[c].z;
            v[c].w = (v[c].w - mu) * rs * g4[c].w + b4[c].w;
            *(float4*)(zr + lane * 4 + 256 * c) = v[c];
        }

        float part[10];
        #pragma unroll
        for (int k = 0; k < 10; k++) part[k] = 0.f;
        #pragma unroll
        for (int c = 0; c < 4; c++) {
            part[9] += v[c].x * v[c].x + v[c].y * v[c].y + v[c].z * v[c].z + v[c].w * v[c].w;
            #pragma unroll
            for (int k = 0; k < 9; k++) {
                float4 p = *(const float4*)&sp[k * HIDDEN + lane * 4 + 256 * c];
                part[k] += v[c].x * p.x + v[c].y * p.y + v[c].z * p.z + v[c].w * p.w;
            }
        }
        #pragma unroll
        for (int m = 1; m < 64; m <<= 1) {
            #pragma unroll
            for (int k = 0; k < 10; k++) part[k] += __shfl_xor(part[k], m);
        }
        if (lane == 0) {
            float inv = 1.0f / (fmaxf(sqrtf(part[9]), 1e-12f) * 0.07f);
            #pragma unroll
            for (int k = 0; k < 9; k++) logits[(size_t)row * NPROTO + k] = part[k] * inv;
        }
    }
}

extern "C" void kernel_launch(void* const* d_in, const int* in_sizes, int n_in,
                              void* d_out, int out_size, void* d_ws, size_t ws_size,
                              hipStream_t stream) {
    const float* h     = (const float*)d_in[0];
    const float* w     = (const float*)d_in[1];
    const float* mask  = (const float*)d_in[2];
    const float* gamma = (const float*)d_in[3];
    const float* beta  = (const float*)d_in[4];
    const float* proto = (const float*)d_in[5];
    float* out    = (float*)d_out;
    float* logits = out;                       // 32768*9 floats
    float* z      = out + (size_t)ZOFF;        // 32768*1024 floats

    char* ws = (char*)d_ws;
    unsigned short* hb = (unsigned short*)ws;                        // 64 MB bf16 h
    unsigned short* wm = (unsigned short*)(ws + 67108864);           // 2 MB bf16 W*mask
    float*          pn = (float*)(ws + 67108864 + 2097152);          // 36 KB normalized protos

    k_conv_h<<<4096, 256, 0, stream>>>(h, hb, MROWS * HIDDEN / 8);
    k_conv_w<<<512, 256, 0, stream>>>(w, mask, wm, HIDDEN * HIDDEN / 8);
    k_proto<<<NPROTO, 256, 0, stream>>>(proto, pn);
    k_gemm<<<2048, 256, 0, stream>>>(hb, wm, z);
    k_ln<<<2048, 256, 0, stream>>>(z, logits, gamma, beta, pn, 2048 * 4);
}